// Round 11
// baseline (222.894 us; speedup 1.0000x reference)
//
#include <hip/hip_runtime.h>
#include <hip/hip_cooperative_groups.h>
#include <math.h>

namespace cg = cooperative_groups;

#define LSEQ 512
#define DMODEL 512
#define DT 64
#define DFF 2048

typedef unsigned short u16;
typedef __attribute__((ext_vector_type(8))) short short8;
typedef __attribute__((ext_vector_type(4))) float f32x4;
typedef __attribute__((ext_vector_type(16))) float f32x16;

__device__ __forceinline__ float wave_sum(float v) {
#pragma unroll
  for (int o = 32; o > 0; o >>= 1) v += __shfl_xor(v, o, 64);
  return v;
}

__device__ __forceinline__ u16 f2bf(float f) {
  unsigned int u = __float_as_uint(f);
  u += 0x7fffu + ((u >> 16) & 1u);
  return (u16)(u >> 16);
}
__device__ __forceinline__ float bf2f(u16 h) {
  return __uint_as_float(((unsigned int)h) << 16);
}
__device__ __forceinline__ void splitbf(float f, u16& h, u16& l) {
  h = f2bf(f);
  l = f2bf(f - bf2f(h));
}

// Swizzled fragment-ready layout for 32x32x16 MFMA operands, matrix X[R][C]:
//   t = r/32, r32 = r%32, kb = c/16, half = (c%16)/8, e = c%8, lane = r32 + 32*half
//   flat(u16) = t*(C*32) + kb*512 + lane*8 + e

// ============================ THE MEGA-KERNEL =======================================
// 256 blocks x 512 threads, cooperative. Stages separated by grid.sync():
//  S0: LN1 (waves 0..1023) + all weight conversion (grid-stride)
//  S1: proj(fc+lin_in bf16x3) + au + a-map        (blocks 0..63, verbatim k_fa)
//  S2: backward affine scan                        (waves 0..127, verbatim k_scan2)
//  S3: (h*y)@low^T + x residual + LN2 -> swizzled  (blocks 0..63, k_midln @512thr)
//  S4: ffn1 = silu(xn2@w1^T+b1) -> swizzled        (all 2048 waves, verbatim)
//  S5: ffn2 = h1@w2^T + b2 + x2 -> out             (2 tiles/block, 4-wave split-K)
__global__ __launch_bounds__(512, 2) void k_mega(
    const float* __restrict__ w1, const float* __restrict__ w2,
    const float* __restrict__ fcw, const float* __restrict__ liw,
    const float* __restrict__ wa, const float* __restrict__ low,
    const float* __restrict__ x, const float* __restrict__ g1,
    const float* __restrict__ be1, const float* __restrict__ fcb,
    const float* __restrict__ lib, const float* __restrict__ hidr,
    const float* __restrict__ hidi, const float* __restrict__ lob,
    const float* __restrict__ g2, const float* __restrict__ be2,
    const float* __restrict__ b1, const float* __restrict__ b2,
    float* __restrict__ y_, float* __restrict__ u_,
    float* __restrict__ ar_, float* __restrict__ ai_,
    float* __restrict__ h_, float* __restrict__ x2_,
    u16* __restrict__ xnh, u16* __restrict__ xnl,
    u16* __restrict__ xn2s, u16* __restrict__ h1s,
    u16* __restrict__ w1s, u16* __restrict__ w2s,
    u16* __restrict__ fclh, u16* __restrict__ fcll,
    u16* __restrict__ wah, u16* __restrict__ wal,
    u16* __restrict__ lowh, u16* __restrict__ lowl,
    float* __restrict__ out)
{
  alignas(16) __shared__ union {
    struct { u16 ush[16][80]; u16 usl[16][80]; } s1;
    struct { u16 hyh[16][80]; u16 hyl[16][80]; float x2s[16][520]; } s3;
    struct { float red[2][4][16][64]; } s5;
  } sm;

  cg::grid_group gg = cg::this_grid();
  const int blk = blockIdx.x, tid = threadIdx.x;
  const int wv = tid >> 6, lane = tid & 63;
  const int gw = blk * 8 + wv;               // global wave id 0..2047
  const int lr = lane & 15, lk = lane >> 4;

  // ---------------- S0: LN1 + weight conversion --------------------------------------
  if (gw < 1024) {                           // LN1: one row per wave
    const int row = gw;
    const float* xr = x + (size_t)row * DMODEL;
    float v[8]; float s = 0.f;
#pragma unroll
    for (int j = 0; j < 8; ++j) { v[j] = xr[lane + 64 * j]; s += v[j]; }
    s = wave_sum(s);
    const float mu = s * (1.f / 512.f);
    float q = 0.f;
#pragma unroll
    for (int j = 0; j < 8; ++j) { float dd = v[j] - mu; q += dd * dd; }
    q = wave_sum(q);
    const float rstd = rsqrtf(q * (1.f / 512.f) + 1e-5f);
#pragma unroll
    for (int j = 0; j < 8; ++j) {
      int idx = lane + 64 * j;
      float o = (v[j] - mu) * rstd * g1[idx] + be1[idx];
      u16 h, l; splitbf(o, h, l);
      xnh[(size_t)row * DMODEL + idx] = h;
      xnl[(size_t)row * DMODEL + idx] = l;
    }
  }
  for (int i = blk * 512 + tid; i < 550912; i += 131072) {  // weights, grid-stride
    if (i < 262144) {                        // w1 (2048x512) -> swizzled bf16
      int r = i >> 7, c0 = (i & 127) << 2;
      float4 v = ((const float4*)w1)[i];
      ushort4 o;
      o.x = f2bf(v.x); o.y = f2bf(v.y); o.z = f2bf(v.z); o.w = f2bf(v.w);
      int lane_s = (r & 31) + (((c0 & 15) >> 3) << 5);
      int flat = (r >> 5) * 16384 + (c0 >> 4) * 512 + lane_s * 8 + (c0 & 7);
      *(ushort4*)(w1s + flat) = o;
    } else if (i < 524288) {                 // w2 (512x2048) -> swizzled bf16
      int ii = i - 262144;
      int r = ii >> 9, c0 = (ii & 511) << 2;
      float4 v = ((const float4*)w2)[ii];
      ushort4 o;
      o.x = f2bf(v.x); o.y = f2bf(v.y); o.z = f2bf(v.z); o.w = f2bf(v.w);
      int lane_s = (r & 31) + (((c0 & 15) >> 3) << 5);
      int flat = (r >> 5) * 65536 + (c0 >> 4) * 512 + lane_s * 8 + (c0 & 7);
      *(ushort4*)(w2s + flat) = o;
    } else {                                 // small weights -> hi/lo bf16
      const float* s; int j; u16 *dh, *dl;
      if (i < 532480)      { s = fcw; j = i - 524288;        dh = fclh; dl = fcll; }
      else if (i < 540672) { s = liw; j = i - 532480 + 8192; dh = fclh; dl = fcll; }
      else if (i < 542720) { s = wa;  j = i - 540672;        dh = wah;  dl = wal;  }
      else                 { s = low; j = i - 542720;        dh = lowh; dl = lowl; }
      int soff = (i < 532480) ? i - 524288 :
                 (i < 540672) ? i - 532480 :
                 (i < 542720) ? i - 540672 : i - 542720;
      float4 v = ((const float4*)s)[soff];
      ushort4 oh, ol;
      splitbf(v.x, oh.x, ol.x); splitbf(v.y, oh.y, ol.y);
      splitbf(v.z, oh.z, ol.z); splitbf(v.w, oh.w, ol.w);
      ((ushort4*)dh)[j] = oh;
      ((ushort4*)dl)[j] = ol;
    }
  }
  gg.sync();

  // ---------------- S1: proj + au (blocks 0..63) -------------------------------------
  if (blk < 64) {
    const int mt = blk;
    {  // phase 1: proj tile, K=512, bf16x3; col-tile = wv
      const size_t aoff = (size_t)(mt * 16 + lr) * DMODEL + lk * 8;
      const size_t boff = (size_t)(wv * 16 + lr) * DMODEL + lk * 8;
      f32x4 acc = {};
#pragma unroll 4
      for (int k = 0; k < DMODEL; k += 32) {
        short8 ah = *(const short8*)(xnh + aoff + k);
        short8 al = *(const short8*)(xnl + aoff + k);
        short8 bh = *(const short8*)(fclh + boff + k);
        short8 bl = *(const short8*)(fcll + boff + k);
        acc = __builtin_amdgcn_mfma_f32_16x16x32_bf16(ah, bh, acc, 0, 0, 0);
        acc = __builtin_amdgcn_mfma_f32_16x16x32_bf16(ah, bl, acc, 0, 0, 0);
        acc = __builtin_amdgcn_mfma_f32_16x16x32_bf16(al, bh, acc, 0, 0, 0);
      }
      const int c = wv * 16 + lr;
#pragma unroll
      for (int j = 0; j < 4; ++j) {
        int rl = lk * 4 + j;
        int row = mt * 16 + rl;
        float v = acc[j];
        if (c < DT) {
          v += fcb[c];
          y_[row * DT + c] = v / (1.f + expf(-v));       // silu gate (fp32)
        } else {
          int d = c - DT;
          v += lib[d];
          u_[row * DT + d] = v;                          // fp32 for scan
          u16 h, l; splitbf(v, h, l);
          sm.s1.ush[rl][d] = h; sm.s1.usl[rl][d] = l;
        }
      }
    }
    __syncthreads();
    {  // phase 2: au tile nt=wv over K=64, bf16x3; then a-map
      const size_t boff = (size_t)(wv * 16 + lr) * DT + lk * 8;
      f32x4 acc = {};
#pragma unroll
      for (int ks = 0; ks < 2; ++ks) {
        short8 ah = *(const short8*)&sm.s1.ush[lr][ks * 32 + lk * 8];
        short8 al = *(const short8*)&sm.s1.usl[lr][ks * 32 + lk * 8];
        short8 bh = *(const short8*)(wah + boff + ks * 32);
        short8 bl = *(const short8*)(wal + boff + ks * 32);
        acc = __builtin_amdgcn_mfma_f32_16x16x32_bf16(ah, bh, acc, 0, 0, 0);
        acc = __builtin_amdgcn_mfma_f32_16x16x32_bf16(ah, bl, acc, 0, 0, 0);
        acc = __builtin_amdgcn_mfma_f32_16x16x32_bf16(al, bh, acc, 0, 0, 0);
      }
      const int c = wv * 16 + lr;
#pragma unroll
      for (int j = 0; j < 4; ++j) {
        float v = acc[j];
        float p = __shfl_xor(v, 1, 64);
        float re = (lane & 1) ? p : v;
        float im = (lane & 1) ? v : p;
        float asq = re * re + im * im;
        float sc = rsqrtf(asq) * expf(-asq);
        int row = mt * 16 + lk * 4 + j;
        int d = c >> 1;
        if (lane & 1) ai_[row * DT + d] = im * sc;
        else          ar_[row * DT + d] = re * sc;
      }
    }
  }
  gg.sync();

  // ---------------- S2: backward affine scan (waves 0..127) --------------------------
  if (gw < 128) {
    const int b = gw >> 6, d = gw & 63;
    const size_t base = (size_t)b * LSEQ * DT + d;
    const int i0 = lane * 8;
    float a_r[8], a_i[8], b_r[8], b_i[8];
#pragma unroll
    for (int e = 0; e < 8; ++e) {
      int i = i0 + e;
      a_r[e] = ar_[base + (size_t)i * DT];
      a_i[e] = ai_[base + (size_t)i * DT];
      if (i >= 2)      { b_r[e] = u_[base + (size_t)(i - 2) * DT]; b_i[e] = 0.f; }
      else if (i == 1) { b_r[e] = hidr[d]; b_i[e] = hidi[d]; }
      else             { b_r[e] = 0.f;     b_i[e] = 0.f; }
    }
    float Ar = 1.f, Ai = 0.f, Br = 0.f, Bi = 0.f;
#pragma unroll
    for (int e = 0; e < 8; ++e) {
      float nBr = fmaf(Ar, b_r[e], fmaf(-Ai, b_i[e], Br));
      float nBi = fmaf(Ar, b_i[e], fmaf( Ai, b_r[e], Bi));
      float nAr = Ar * a_r[e] - Ai * a_i[e];
      float nAi = Ar * a_i[e] + Ai * a_r[e];
      Ar = nAr; Ai = nAi; Br = nBr; Bi = nBi;
    }
#pragma unroll
    for (int dlt = 1; dlt < 64; dlt <<= 1) {
      float Ar2 = __shfl_down(Ar, dlt, 64);
      float Ai2 = __shfl_down(Ai, dlt, 64);
      float Br2 = __shfl_down(Br, dlt, 64);
      float Bi2 = __shfl_down(Bi, dlt, 64);
      if (lane + dlt < 64) {
        float nAr = Ar * Ar2 - Ai * Ai2;
        float nAi = Ar * Ai2 + Ai * Ar2;
        float nBr = fmaf(Ar, Br2, fmaf(-Ai, Bi2, Br));
        float nBi = fmaf(Ar, Bi2, fmaf( Ai, Br2, Bi));
        Ar = nAr; Ai = nAi; Br = nBr; Bi = nBi;
      }
    }
    float A1r = __shfl_down(Ar, 1, 64), A1i = __shfl_down(Ai, 1, 64);
    float B1r = __shfl_down(Br, 1, 64), B1i = __shfl_down(Bi, 1, 64);
    if (lane == 63) { A1r = 1.f; A1i = 0.f; B1r = 0.f; B1i = 0.f; }
    const float r512 = u_[base + (size_t)(LSEQ - 2) * DT];
    float rr = fmaf(A1r, r512, B1r);
    float ri = fmaf(A1i, r512, B1i);
    const float uL = u_[base + (size_t)(LSEQ - 1) * DT];
#pragma unroll
    for (int e = 7; e >= 0; --e) {
      int i = i0 + e;
      float nr = fmaf(a_r[e], rr, fmaf(-a_i[e], ri, b_r[e]));
      float ni = fmaf(a_r[e], ri, fmaf( a_i[e], rr, b_i[e]));
      rr = nr; ri = ni;
      float outv = rr;
      if (i == LSEQ - 1) outv += uL;
      h_[base + (size_t)i * DT] = outv;
    }
  }
  gg.sync();

  // ---------------- S3: mid GEMM + residual + LN2 (blocks 0..63, 512 thr) ------------
  if (blk < 64) {
    const int mt = blk;
#pragma unroll
    for (int it = 0; it < 2; ++it) {         // phase 0: hy hi/lo (1024 elems)
      int idx = it * 512 + tid;
      int r = idx >> 6, d = idx & 63;
      int row = mt * 16 + r;
      float v = h_[row * DT + d] * y_[row * DT + d];
      u16 hh, ll; splitbf(v, hh, ll);
      sm.s3.hyh[r][d] = hh; sm.s3.hyl[r][d] = ll;
    }
    __syncthreads();
#pragma unroll
    for (int t = 0; t < 4; ++t) {            // phase 1: tiles nt = wv*4+t
      const int nt = wv * 4 + t;
      const size_t boff = (size_t)(nt * 16 + lr) * DT + lk * 8;
      f32x4 acc = {};
#pragma unroll
      for (int ks = 0; ks < 2; ++ks) {
        short8 ah = *(const short8*)&sm.s3.hyh[lr][ks * 32 + lk * 8];
        short8 al = *(const short8*)&sm.s3.hyl[lr][ks * 32 + lk * 8];
        short8 bh = *(const short8*)(lowh + boff + ks * 32);
        short8 bl = *(const short8*)(lowl + boff + ks * 32);
        acc = __builtin_amdgcn_mfma_f32_16x16x32_bf16(ah, bh, acc, 0, 0, 0);
        acc = __builtin_amdgcn_mfma_f32_16x16x32_bf16(ah, bl, acc, 0, 0, 0);
        acc = __builtin_amdgcn_mfma_f32_16x16x32_bf16(al, bh, acc, 0, 0, 0);
      }
      const int c = nt * 16 + lr;
#pragma unroll
      for (int j = 0; j < 4; ++j) {
        int rl = lk * 4 + j;
        int row = mt * 16 + rl;
        float v = acc[j] + lob[c] + x[(size_t)row * DMODEL + c];
        sm.s3.x2s[rl][c] = v;
        x2_[(size_t)row * DMODEL + c] = v;
      }
    }
    __syncthreads();
#pragma unroll
    for (int rr2 = 0; rr2 < 2; ++rr2) {      // phase 2: LN2, 2 rows/wave, swizzled
      const int r = wv * 2 + rr2;
      const int row = mt * 16 + r;
      float v[8]; float s = 0.f;
#pragma unroll
      for (int j = 0; j < 8; ++j) { v[j] = sm.s3.x2s[r][lane + 64 * j]; s += v[j]; }
      s = wave_sum(s);
      const float mu = s * (1.f / 512.f);
      float q = 0.f;
#pragma unroll
      for (int j = 0; j < 8; ++j) { float dd = v[j] - mu; q += dd * dd; }
      q = wave_sum(q);
      const float rstd = rsqrtf(q * (1.f / 512.f) + 1e-5f);
      const int t32 = row >> 5, r32 = row & 31;
#pragma unroll
      for (int j = 0; j < 8; ++j) {
        int idx = lane + 64 * j;
        float o = (v[j] - mu) * rstd * g2[idx] + be2[idx];
        int lane_s = r32 + (((idx & 15) >> 3) << 5);
        xn2s[t32 * 16384 + (idx >> 4) * 512 + lane_s * 8 + (idx & 7)] = f2bf(o);
      }
    }
  }
  gg.sync();

  // ---------------- S4: ffn1 (all 2048 waves, barrier-free, swizzled I/O) ------------
  {
    const int mt = gw & 31, nt = gw >> 5;
    const u16* a = xn2s + mt * 16384 + lane * 8;
    const u16* b = w1s + nt * 16384 + lane * 8;
    f32x16 acc = {};
#pragma unroll 8
    for (int kb = 0; kb < 32; ++kb)
      acc = __builtin_amdgcn_mfma_f32_32x32x16_bf16(*(const short8*)(a + kb * 512),
                                                    *(const short8*)(b + kb * 512),
                                                    acc, 0, 0, 0);
    const int l31 = lane & 31, hi = lane >> 5;
    const int col = nt * 32 + l31;
    const float bb = b1[col];
    const int kb_c = col >> 4;
    const int half_c = (col & 15) >> 3, e_c = col & 7;
#pragma unroll
    for (int r = 0; r < 16; ++r) {
      int row32 = (r & 3) + 8 * (r >> 2) + 4 * hi;
      float v = acc[r] + bb;
      v = v / (1.f + expf(-v));              // silu
      int lane_s = row32 + (half_c << 5);
      h1s[mt * 65536 + kb_c * 512 + lane_s * 8 + e_c] = f2bf(v);
    }
  }
  gg.sync();

  // ---------------- S5: ffn2 (2 tiles/block, 4-wave split-K, fused epilogue) ---------
  {
    const int sub = wv >> 2, wq = wv & 3;
    const int ti = blk * 2 + sub;            // 0..511
    const int mt = ti & 31, nt = ti >> 5;    // 32 x 16 tiles
    const u16* a = h1s + mt * 65536 + wq * 16384 + lane * 8;
    const u16* b = w2s + nt * 65536 + wq * 16384 + lane * 8;
    f32x16 acc = {};
#pragma unroll 8
    for (int kb = 0; kb < 32; ++kb)
      acc = __builtin_amdgcn_mfma_f32_32x32x16_bf16(*(const short8*)(a + kb * 512),
                                                    *(const short8*)(b + kb * 512),
                                                    acc, 0, 0, 0);
#pragma unroll
    for (int r = 0; r < 16; ++r) sm.s5.red[sub][wq][r][lane] = acc[r];
    __syncthreads();
    const int tloc = wq * 64 + lane;         // 0..255 within this tile's 4 waves
    for (int s = tloc; s < 1024; s += 256) {
      int r = s >> 6, l = s & 63;
      float v = sm.s5.red[sub][0][r][l] + sm.s5.red[sub][1][r][l] +
                sm.s5.red[sub][2][r][l] + sm.s5.red[sub][3][r][l];
      int row = mt * 32 + (r & 3) + 8 * (r >> 2) + 4 * (l >> 5);
      int col = nt * 32 + (l & 31);
      out[(size_t)row * DMODEL + col] =
          v + b2[col] + x2_[(size_t)row * DMODEL + col];
    }
  }
}

// ---------------- launch -------------------------------------------------------------
extern "C" void kernel_launch(void* const* d_in, const int* in_sizes, int n_in,
                              void* d_out, int out_size, void* d_ws, size_t ws_size,
                              hipStream_t stream) {
  const float* x    = (const float*)d_in[0];
  const float* ln1g = (const float*)d_in[1];
  const float* ln1b = (const float*)d_in[2];
  const float* fcw  = (const float*)d_in[3];
  const float* fcb  = (const float*)d_in[4];
  const float* liw  = (const float*)d_in[5];
  const float* lib  = (const float*)d_in[6];
  const float* wa   = (const float*)d_in[7];
  const float* hidr = (const float*)d_in[8];
  const float* hidi = (const float*)d_in[9];
  const float* low  = (const float*)d_in[10];
  const float* lob  = (const float*)d_in[11];
  const float* ln2g = (const float*)d_in[12];
  const float* ln2b = (const float*)d_in[13];
  const float* w1   = (const float*)d_in[14];
  const float* b1   = (const float*)d_in[15];
  const float* w2   = (const float*)d_in[16];
  const float* b2   = (const float*)d_in[17];
  float* out = (float*)d_out;
  float* ws  = (float*)d_ws;

  float* y_   = ws;                            // 65536
  float* u_   = y_  + 65536;
  float* ar_  = u_  + 65536;
  float* ai_  = ar_ + 65536;
  float* h_   = ai_ + 65536;
  float* x2_  = h_  + 65536;                   // 524288
  u16* p = (u16*)(x2_ + 524288);
  u16* xnh  = p;            p += 524288;
  u16* xnl  = p;            p += 524288;
  u16* xn2s = p;            p += 524288;       // swizzled
  u16* h1s  = p;            p += 2097152;      // swizzled
  u16* w1s  = p;            p += 1048576;      // swizzled
  u16* w2s  = p;            p += 1048576;      // swizzled
  u16* fclh = p;            p += 65536;
  u16* fcll = p;            p += 65536;
  u16* wah  = p;            p += 8192;
  u16* wal  = p;            p += 8192;
  u16* lowh = p;            p += 32768;
  u16* lowl = p;            p += 32768;

  void* kp[] = {
    (void*)&w1, (void*)&w2, (void*)&fcw, (void*)&liw, (void*)&wa, (void*)&low,
    (void*)&x, (void*)&ln1g, (void*)&ln1b, (void*)&fcb, (void*)&lib,
    (void*)&hidr, (void*)&hidi, (void*)&lob, (void*)&ln2g, (void*)&ln2b,
    (void*)&b1, (void*)&b2,
    (void*)&y_, (void*)&u_, (void*)&ar_, (void*)&ai_, (void*)&h_, (void*)&x2_,
    (void*)&xnh, (void*)&xnl, (void*)&xn2s, (void*)&h1s,
    (void*)&w1s, (void*)&w2s, (void*)&fclh, (void*)&fcll,
    (void*)&wah, (void*)&wal, (void*)&lowh, (void*)&lowl,
    (void*)&out
  };
  hipLaunchCooperativeKernel((const void*)k_mega, dim3(256), dim3(512),
                             kp, 0, stream);
}

// Round 12
// 53.717 us; speedup vs baseline: 4.1495x; 4.1495x over previous
//
#include <hip/hip_runtime.h>
#include <math.h>

#define LSEQ 512
#define DMODEL 512
#define DT 64
#define DFF 2048

typedef unsigned short u16;
typedef __attribute__((ext_vector_type(8))) short short8;
typedef __attribute__((ext_vector_type(4))) float f32x4;
typedef __attribute__((ext_vector_type(16))) float f32x16;

__device__ __forceinline__ float wave_sum(float v) {
#pragma unroll
  for (int o = 32; o > 0; o >>= 1) v += __shfl_xor(v, o, 64);
  return v;
}

__device__ __forceinline__ u16 f2bf(float f) {
  unsigned int u = __float_as_uint(f);
  u += 0x7fffu + ((u >> 16) & 1u);
  return (u16)(u >> 16);
}
__device__ __forceinline__ float bf2f(u16 h) {
  return __uint_as_float(((unsigned int)h) << 16);
}
__device__ __forceinline__ void splitbf(float f, u16& h, u16& l) {
  h = f2bf(f);
  l = f2bf(f - bf2f(h));
}
// load 8 fp32 and split into hi/lo bf16 fragments (identical values to pre-converted)
__device__ __forceinline__ void split8(const float* __restrict__ p,
                                       short8& bh, short8& bl) {
  float4 a = *(const float4*)p;
  float4 b = *(const float4*)(p + 4);
  float vv[8] = {a.x, a.y, a.z, a.w, b.x, b.y, b.z, b.w};
#pragma unroll
  for (int e = 0; e < 8; ++e) {
    u16 h, l; splitbf(vv[e], h, l);
    bh[e] = (short)h; bl[e] = (short)l;
  }
}

// Swizzled fragment-ready layout for 32x32x16 MFMA operands, matrix X[R][C]:
//   t = r/32, r32 = r%32, kb = c/16, half = (c%16)/8, e = c%8, lane = r32 + 32*half
//   flat(u16) = t*(C*32) + kb*512 + lane*8 + e

// ---------------- k_fa: blocks 0..63: LN1 + proj(fc+lin_in bf16x3) + au + a-map ------
//                  blocks 64..319: w1/w2 -> swizzled bf16 (independent, overlapped)
__global__ __launch_bounds__(512) void k_fa(
    const float* __restrict__ x, const float* __restrict__ g1,
    const float* __restrict__ be1,
    const float* __restrict__ fcw, const float* __restrict__ liw,
    const float* __restrict__ wa,
    const float* __restrict__ fcb, const float* __restrict__ lib,
    const float* __restrict__ w1, const float* __restrict__ w2,
    float* __restrict__ y_o, float* __restrict__ u_o,
    float* __restrict__ ar_o, float* __restrict__ ai_o,
    u16* __restrict__ w1s, u16* __restrict__ w2s)
{
  const int blk = blockIdx.x;
  if (blk >= 64) {                           // ---- w1/w2 swizzle conversion ----
    for (int i = (blk - 64) * 512 + threadIdx.x; i < 524288; i += 131072) {
      if (i < 262144) {                      // w1 (2048x512)
        int r = i >> 7, c0 = (i & 127) << 2;
        float4 v = ((const float4*)w1)[i];
        ushort4 o;
        o.x = f2bf(v.x); o.y = f2bf(v.y); o.z = f2bf(v.z); o.w = f2bf(v.w);
        int lane_s = (r & 31) + (((c0 & 15) >> 3) << 5);
        int flat = (r >> 5) * 16384 + (c0 >> 4) * 512 + lane_s * 8 + (c0 & 7);
        *(ushort4*)(w1s + flat) = o;
      } else {                               // w2 (512x2048)
        int ii = i - 262144;
        int r = ii >> 9, c0 = (ii & 511) << 2;
        float4 v = ((const float4*)w2)[ii];
        ushort4 o;
        o.x = f2bf(v.x); o.y = f2bf(v.y); o.z = f2bf(v.z); o.w = f2bf(v.w);
        int lane_s = (r & 31) + (((c0 & 15) >> 3) << 5);
        int flat = (r >> 5) * 65536 + (c0 >> 4) * 512 + lane_s * 8 + (c0 & 7);
        *(ushort4*)(w2s + flat) = o;
      }
    }
    return;
  }
  // ---- compute blocks: 16-row tile mt ----
  __shared__ __align__(16) u16 xsh[16][520];
  __shared__ __align__(16) u16 xsl[16][520];
  __shared__ __align__(16) u16 ush[16][80];
  __shared__ __align__(16) u16 usl[16][80];
  const int tid = threadIdx.x;
  const int wv = tid >> 6, lane = tid & 63;
  const int lr = lane & 15, lk = lane >> 4;
  const int mt = blk;

  // LN1 for own 16 rows -> LDS hi/lo (verbatim math)
#pragma unroll
  for (int rr = 0; rr < 2; ++rr) {
    const int r = wv * 2 + rr;
    const int row = mt * 16 + r;
    const float* xr = x + (size_t)row * DMODEL;
    float v[8]; float s = 0.f;
#pragma unroll
    for (int j = 0; j < 8; ++j) { v[j] = xr[lane + 64 * j]; s += v[j]; }
    s = wave_sum(s);
    const float mu = s * (1.f / 512.f);
    float q = 0.f;
#pragma unroll
    for (int j = 0; j < 8; ++j) { float dd = v[j] - mu; q += dd * dd; }
    q = wave_sum(q);
    const float rstd = rsqrtf(q * (1.f / 512.f) + 1e-5f);
#pragma unroll
    for (int j = 0; j < 8; ++j) {
      int idx = lane + 64 * j;
      float o = (v[j] - mu) * rstd * g1[idx] + be1[idx];
      u16 h, l; splitbf(o, h, l);
      xsh[r][idx] = h;
      xsl[r][idx] = l;
    }
  }
  __syncthreads();

  const int c = wv * 16 + lr;
  {  // proj tile, K=512, bf16x3; A from LDS, B from fp32 split on the fly
    const float* brow = (c < DT) ? (fcw + (size_t)c * DMODEL)
                                 : (liw + (size_t)(c - DT) * DMODEL);
    f32x4 acc = {};
#pragma unroll 4
    for (int k = 0; k < DMODEL; k += 32) {
      short8 ah = *(const short8*)&xsh[lr][k + lk * 8];
      short8 al = *(const short8*)&xsl[lr][k + lk * 8];
      short8 bh, bl;
      split8(brow + k + lk * 8, bh, bl);
      acc = __builtin_amdgcn_mfma_f32_16x16x32_bf16(ah, bh, acc, 0, 0, 0);
      acc = __builtin_amdgcn_mfma_f32_16x16x32_bf16(ah, bl, acc, 0, 0, 0);
      acc = __builtin_amdgcn_mfma_f32_16x16x32_bf16(al, bh, acc, 0, 0, 0);
    }
#pragma unroll
    for (int j = 0; j < 4; ++j) {
      int rl = lk * 4 + j;
      int row = mt * 16 + rl;
      float v = acc[j];
      if (c < DT) {
        v += fcb[c];
        y_o[row * DT + c] = v / (1.f + expf(-v));        // silu gate (fp32)
      } else {
        int d = c - DT;
        v += lib[d];
        u_o[row * DT + d] = v;                           // fp32 for scan
        u16 h, l; splitbf(v, h, l);
        ush[rl][d] = h; usl[rl][d] = l;
      }
    }
  }
  __syncthreads();
  {  // au tile nt=wv over K=64, bf16x3; wa fp32 split on the fly; then a-map
    const float* warow = wa + (size_t)c * DT;
    f32x4 acc = {};
#pragma unroll
    for (int ks = 0; ks < 2; ++ks) {
      short8 ah = *(const short8*)&ush[lr][ks * 32 + lk * 8];
      short8 al = *(const short8*)&usl[lr][ks * 32 + lk * 8];
      short8 bh, bl;
      split8(warow + ks * 32 + lk * 8, bh, bl);
      acc = __builtin_amdgcn_mfma_f32_16x16x32_bf16(ah, bh, acc, 0, 0, 0);
      acc = __builtin_amdgcn_mfma_f32_16x16x32_bf16(ah, bl, acc, 0, 0, 0);
      acc = __builtin_amdgcn_mfma_f32_16x16x32_bf16(al, bh, acc, 0, 0, 0);
    }
#pragma unroll
    for (int j = 0; j < 4; ++j) {
      float v = acc[j];
      float p = __shfl_xor(v, 1, 64);
      float re = (lane & 1) ? p : v;
      float im = (lane & 1) ? v : p;
      float asq = re * re + im * im;
      float sc = rsqrtf(asq) * expf(-asq);
      int row = mt * 16 + lk * 4 + j;
      int d = c >> 1;
      if (lane & 1) ai_o[row * DT + d] = im * sc;
      else          ar_o[row * DT + d] = re * sc;
    }
  }
}

// ---------------- parallel backward affine scan (unchanged) --------------------------
__global__ __launch_bounds__(64) void k_scan2(
    const float* __restrict__ u, const float* __restrict__ ar, const float* __restrict__ ai,
    const float* __restrict__ hr, const float* __restrict__ hi, float* __restrict__ h_o)
{
  const int blk = blockIdx.x;             // 0..127
  const int b = blk >> 6, d = blk & 63;
  const int lane = threadIdx.x;           // 0..63
  const size_t base = (size_t)b * LSEQ * DT + d;
  const int i0 = lane * 8;

  float a_r[8], a_i[8], b_r[8], b_i[8];
#pragma unroll
  for (int e = 0; e < 8; ++e) {
    int i = i0 + e;
    a_r[e] = ar[base + (size_t)i * DT];
    a_i[e] = ai[base + (size_t)i * DT];
    if (i >= 2)      { b_r[e] = u[base + (size_t)(i - 2) * DT]; b_i[e] = 0.f; }
    else if (i == 1) { b_r[e] = hr[d]; b_i[e] = hi[d]; }
    else             { b_r[e] = 0.f;   b_i[e] = 0.f; }
  }

  float Ar = 1.f, Ai = 0.f, Br = 0.f, Bi = 0.f;
#pragma unroll
  for (int e = 0; e < 8; ++e) {
    float nBr = fmaf(Ar, b_r[e], fmaf(-Ai, b_i[e], Br));
    float nBi = fmaf(Ar, b_i[e], fmaf( Ai, b_r[e], Bi));
    float nAr = Ar * a_r[e] - Ai * a_i[e];
    float nAi = Ar * a_i[e] + Ai * a_r[e];
    Ar = nAr; Ai = nAi; Br = nBr; Bi = nBi;
  }

#pragma unroll
  for (int dlt = 1; dlt < 64; dlt <<= 1) {
    float Ar2 = __shfl_down(Ar, dlt, 64);
    float Ai2 = __shfl_down(Ai, dlt, 64);
    float Br2 = __shfl_down(Br, dlt, 64);
    float Bi2 = __shfl_down(Bi, dlt, 64);
    if (lane + dlt < 64) {
      float nAr = Ar * Ar2 - Ai * Ai2;
      float nAi = Ar * Ai2 + Ai * Ar2;
      float nBr = fmaf(Ar, Br2, fmaf(-Ai, Bi2, Br));
      float nBi = fmaf(Ar, Bi2, fmaf( Ai, Br2, Bi));
      Ar = nAr; Ai = nAi; Br = nBr; Bi = nBi;
    }
  }

  float A1r = __shfl_down(Ar, 1, 64), A1i = __shfl_down(Ai, 1, 64);
  float B1r = __shfl_down(Br, 1, 64), B1i = __shfl_down(Bi, 1, 64);
  if (lane == 63) { A1r = 1.f; A1i = 0.f; B1r = 0.f; B1i = 0.f; }
  const float r512 = u[base + (size_t)(LSEQ - 2) * DT];
  float rr = fmaf(A1r, r512, B1r);
  float ri = fmaf(A1i, r512, B1i);

  const float uL = u[base + (size_t)(LSEQ - 1) * DT];
#pragma unroll
  for (int e = 7; e >= 0; --e) {
    int i = i0 + e;
    float nr = fmaf(a_r[e], rr, fmaf(-a_i[e], ri, b_r[e]));
    float ni = fmaf(a_r[e], ri, fmaf( a_i[e], rr, b_i[e]));
    rr = nr; ri = ni;
    float outv = rr;
    if (i == LSEQ - 1) outv += uL;
    h_o[base + (size_t)i * DT] = outv;
  }
}

// ---------------- k_midln: x2 = (h*y)@low^T+lob+x (bf16x3), LN2 -> SWIZZLED xn2 ------
// 64 blocks x 1024 thr; low read as fp32 + split on the fly (identical values).
__global__ __launch_bounds__(1024) void k_midln(
    const float* __restrict__ h, const float* __restrict__ y,
    const float* __restrict__ low, const float* __restrict__ lob,
    const float* __restrict__ x, const float* __restrict__ g2,
    const float* __restrict__ be2,
    float* __restrict__ x2_o, u16* __restrict__ xn2s)
{
  __shared__ __align__(16) u16 hyh[16][80];
  __shared__ __align__(16) u16 hyl[16][80];
  __shared__ float x2s[16][520];
  const int tid = threadIdx.x;
  const int w = tid >> 6, lane = tid & 63;
  const int lr = lane & 15, lk = lane >> 4;
  const int mt = blockIdx.x;

  {                                            // phase 0: hy hi/lo
    int r = tid >> 6, d = tid & 63;
    int row = mt * 16 + r;
    float v = h[row * DT + d] * y[row * DT + d];
    u16 hh, ll; splitbf(v, hh, ll);
    hyh[r][d] = hh; hyl[r][d] = ll;
  }
  __syncthreads();

#pragma unroll
  for (int t = 0; t < 2; ++t) {                // phase 1: tiles nt = w*2+t
    const int nt = w * 2 + t;
    const float* brow = low + (size_t)(nt * 16 + lr) * DT;
    f32x4 acc = {};
#pragma unroll
    for (int ks = 0; ks < 2; ++ks) {
      short8 ah = *(const short8*)&hyh[lr][ks * 32 + lk * 8];
      short8 al = *(const short8*)&hyl[lr][ks * 32 + lk * 8];
      short8 bh, bl;
      split8(brow + ks * 32 + lk * 8, bh, bl);
      acc = __builtin_amdgcn_mfma_f32_16x16x32_bf16(ah, bh, acc, 0, 0, 0);
      acc = __builtin_amdgcn_mfma_f32_16x16x32_bf16(ah, bl, acc, 0, 0, 0);
      acc = __builtin_amdgcn_mfma_f32_16x16x32_bf16(al, bh, acc, 0, 0, 0);
    }
    const int c = nt * 16 + lr;
#pragma unroll
    for (int j = 0; j < 4; ++j) {
      int rl = lk * 4 + j;
      int row = mt * 16 + rl;
      float v = acc[j] + lob[c] + x[(size_t)row * DMODEL + c];
      x2s[rl][c] = v;
      x2_o[(size_t)row * DMODEL + c] = v;
    }
  }
  __syncthreads();

  {                                            // phase 2: LN2, row w; swizzled store
    const int r = w;
    const int row = mt * 16 + r;
    float v[8]; float s = 0.f;
#pragma unroll
    for (int j = 0; j < 8; ++j) { v[j] = x2s[r][lane + 64 * j]; s += v[j]; }
    s = wave_sum(s);
    const float mu = s * (1.f / 512.f);
    float q = 0.f;
#pragma unroll
    for (int j = 0; j < 8; ++j) { float dd = v[j] - mu; q += dd * dd; }
    q = wave_sum(q);
    const float rstd = rsqrtf(q * (1.f / 512.f) + 1e-5f);
    const int t32 = row >> 5, r32 = row & 31;
#pragma unroll
    for (int j = 0; j < 8; ++j) {
      int idx = lane + 64 * j;
      float o = (v[j] - mu) * rstd * g2[idx] + be2[idx];
      int lane_s = r32 + (((idx & 15) >> 3) << 5);
      xn2s[t32 * 16384 + (idx >> 4) * 512 + lane_s * 8 + (idx & 7)] = f2bf(o);
    }
  }
}

// ---------------- k_ffn1: h1 = silu(xn2 @ w1^T + b1); barrier-free, swizzled I/O -----
__global__ __launch_bounds__(256) void k_ffn1(
    const u16* __restrict__ As, const u16* __restrict__ Bs,
    const float* __restrict__ bias, u16* __restrict__ Cs)
{
  const int w = threadIdx.x >> 6, lane = threadIdx.x & 63;
  const int mt = blockIdx.x, nt = blockIdx.y * 4 + w;
  const u16* a = As + mt * 16384 + lane * 8;
  const u16* b = Bs + nt * 16384 + lane * 8;
  f32x16 acc = {};
#pragma unroll 8
  for (int kb = 0; kb < 32; ++kb)
    acc = __builtin_amdgcn_mfma_f32_32x32x16_bf16(*(const short8*)(a + kb * 512),
                                                  *(const short8*)(b + kb * 512),
                                                  acc, 0, 0, 0);
  const int l31 = lane & 31, hi = lane >> 5;
  const int col = nt * 32 + l31;
  const float bb = bias[col];
  const int kb_c = col >> 4;
  const int half_c = (col & 15) >> 3, e_c = col & 7;
#pragma unroll
  for (int r = 0; r < 16; ++r) {
    int row32 = (r & 3) + 8 * (r >> 2) + 4 * hi;
    float v = acc[r] + bb;
    v = v / (1.f + expf(-v));                  // silu
    int lane_s = row32 + (half_c << 5);
    Cs[mt * 65536 + kb_c * 512 + lane_s * 8 + e_c] = f2bf(v);
  }
}

// ---------------- k_ffn2: out = h1 @ w2^T + b2 + x2; 4-wave in-block split-K ---------
__global__ __launch_bounds__(256) void k_ffn2(
    const u16* __restrict__ As, const u16* __restrict__ Bs,
    const float* __restrict__ b2, const float* __restrict__ x2,
    float* __restrict__ out)
{
  __shared__ float red[4][16][64];
  const int w = threadIdx.x >> 6, lane = threadIdx.x & 63;
  const int mt = blockIdx.x, nt = blockIdx.y;
  const u16* a = As + mt * 65536 + w * 32 * 512 + lane * 8;
  const u16* b = Bs + nt * 65536 + w * 32 * 512 + lane * 8;
  f32x16 acc = {};
#pragma unroll 8
  for (int kb = 0; kb < 32; ++kb)
    acc = __builtin_amdgcn_mfma_f32_32x32x16_bf16(*(const short8*)(a + kb * 512),
                                                  *(const short8*)(b + kb * 512),
                                                  acc, 0, 0, 0);
#pragma unroll
  for (int r = 0; r < 16; ++r) red[w][r][lane] = acc[r];
  __syncthreads();
  for (int s = threadIdx.x; s < 1024; s += 256) {
    int r = s >> 6, l = s & 63;
    float v = red[0][r][l] + red[1][r][l] + red[2][r][l] + red[3][r][l];
    int row = mt * 32 + (r & 3) + 8 * (r >> 2) + 4 * (l >> 5);
    int col = nt * 32 + (l & 31);
    out[(size_t)row * DMODEL + col] =
        v + b2[col] + x2[(size_t)row * DMODEL + col];
  }
}

// ---------------- launch -------------------------------------------------------------
extern "C" void kernel_launch(void* const* d_in, const int* in_sizes, int n_in,
                              void* d_out, int out_size, void* d_ws, size_t ws_size,
                              hipStream_t stream) {
  const float* x    = (const float*)d_in[0];
  const float* ln1g = (const float*)d_in[1];
  const float* ln1b = (const float*)d_in[2];
  const float* fcw  = (const float*)d_in[3];
  const float* fcb  = (const float*)d_in[4];
  const float* liw  = (const float*)d_in[5];
  const float* lib  = (const float*)d_in[6];
  const float* wa   = (const float*)d_in[7];
  const float* hidr = (const float*)d_in[8];
  const float* hidi = (const float*)d_in[9];
  const float* low  = (const float*)d_in[10];
  const float* lob  = (const float*)d_in[11];
  const float* ln2g = (const float*)d_in[12];
  const float* ln2b = (const float*)d_in[13];
  const float* w1   = (const float*)d_in[14];
  const float* b1   = (const float*)d_in[15];
  const float* w2   = (const float*)d_in[16];
  const float* b2   = (const float*)d_in[17];
  float* out = (float*)d_out;
  float* ws  = (float*)d_ws;

  float* y_   = ws;                            // 65536
  float* u_   = y_  + 65536;
  float* ar_  = u_  + 65536;
  float* ai_  = ar_ + 65536;
  float* h_   = ai_ + 65536;
  float* x2_  = h_  + 65536;                   // 524288
  u16* p = (u16*)(x2_ + 524288);
  u16* xn2s = p;            p += 524288;       // swizzled
  u16* h1s  = p;            p += 2097152;      // swizzled
  u16* w1s  = p;            p += 1048576;      // swizzled
  u16* w2s  = p;            p += 1048576;      // swizzled

  k_fa<<<320, 512, 0, stream>>>(x, ln1g, ln1b, fcw, liw, wa, fcb, lib, w1, w2,
                                y_, u_, ar_, ai_, w1s, w2s);
  k_scan2<<<128, 64, 0, stream>>>(u_, ar_, ai_, hidr, hidi, h_);
  k_midln<<<64, 1024, 0, stream>>>(h_, y_, low, lob, x, ln2g, ln2b, x2_, xn2s);
  k_ffn1<<<dim3(32, 16), 256, 0, stream>>>(xn2s, w1s, b1, h1s);
  k_ffn2<<<dim3(32, 16), 256, 0, stream>>>(h1s, w2s, b2, x2_, out);
}